// Round 13
// baseline (265.360 us; speedup 1.0000x reference)
//
#include <hip/hip_runtime.h>

// Problem constants
#define B_  2
#define N_  20000
#define C_  256
#define K_  5000
#define M_  (B_ * K_)     // 10000
#define NBIN_ 2048
#define AST_ 264          // act LDS row stride (shorts): 16B-aligned
#define NCH_ 79           // score chunks of 256 (79*256 = 20224 >= N)

typedef __attribute__((ext_vector_type(8))) short bf16x8;
typedef __attribute__((ext_vector_type(4))) float f32x4;
typedef __attribute__((ext_vector_type(2))) unsigned long long ull2;

__device__ __forceinline__ unsigned short f2bf(float x) {
  unsigned u = __float_as_uint(x);
  return (unsigned short)((u + 0x7fffu + ((u >> 16) & 1u)) >> 16);
}
__device__ __forceinline__ float bf2f(unsigned short h) {
  return __uint_as_float(((unsigned)h) << 16);
}
__device__ __forceinline__ unsigned fkey(float f) {
  unsigned u = __float_as_uint(f);
  return (u & 0x80000000u) ? ~u : (u | 0x80000000u);
}
// monotone linear bin; only hist/compact CONSISTENCY matters (upward-closed set)
__device__ __forceinline__ int binof(float s) {
  int b = (int)(s * 2048.0f);
  return b < 0 ? 0 : (b > 2047 ? 2047 : b);
}
__device__ __forceinline__ bf16x8 as_bf(uint4 v) {
  union { uint4 u; bf16x8 b; } c; c.u = v; return c.b;
}

// ---------------------------------------------------------------------------
// K1: fused select+compact (deterministic per-chunk slots, no global counter,
// nothing needs pre-zeroing) + W bf16 fragment-order pack.
//  u < 158:  block (b = u/79, ch = u%79): LDS histogram over full batch ->
//            selB (all blocks compute identical value); then compact this
//            chunk's survivors into ck[b][ch][0..cnt) via wave-ballot scan,
//            write sc[b][ch] = cnt, and default rnk = K_ for its 256 n's.
//  u >= 158: pack W[l][o][k] -> Wp[l][w8][ks][oi2][lane][j] (see k_mlp6).
__global__ __launch_bounds__(256) void k_selpack(const float* __restrict__ score,
                                                 const float* __restrict__ W,
                                                 unsigned short* __restrict__ Whi,
                                                 unsigned long long* __restrict__ ck,
                                                 int* __restrict__ sc,
                                                 int* __restrict__ rnk) {
  const int u = blockIdx.x;
  const int t = threadIdx.x;
  if (u < NCH_ * B_) {
    const int b = u / NCH_, ch = u % NCH_;
    const float* s = score + b * N_;
    __shared__ int h[NBIN_];
    __shared__ int chs[256];
    __shared__ int res[1];
    __shared__ int wtot[4], woff[4];
    for (int i = t; i < NBIN_; i += 256) h[i] = 0;
    __syncthreads();
    for (int i = t; i < N_; i += 256) atomicAdd(&h[binof(s[i])], 1);
    __syncthreads();
    int sum = 0;
#pragma unroll
    for (int j = 0; j < 8; ++j) sum += h[t * 8 + j];
    chs[t] = sum;
    __syncthreads();
    for (int off = 1; off < 256; off <<= 1) {
      int v = chs[t] + ((t + off < 256) ? chs[t + off] : 0);
      __syncthreads();
      chs[t] = v;
      __syncthreads();
    }
    const int above = (t + 1 < 256) ? chs[t + 1] : 0;
    if (above < K_ && K_ <= chs[t]) {
      int acc = above;
      for (int i = 7; i >= 0; --i) {
        const int bin = t * 8 + i;
        if (acc + h[bin] >= K_) { res[0] = bin; break; }
        acc += h[bin];
      }
    }
    __syncthreads();
    const int selB = res[0];
    // compact this chunk deterministically
    const int n = ch * 256 + t;
    bool pred = false;
    unsigned long long key = 0ULL;
    if (n < N_) {
      rnk[b * N_ + n] = K_;
      const float sv = s[n];
      pred = (binof(sv) >= selB);
      key = ((unsigned long long)fkey(sv) << 32) | (unsigned)(N_ - 1 - n);
    }
    const unsigned long long mask = __ballot(pred);
    const int lane = t & 63, wv = t >> 6;
    if (lane == 0) wtot[wv] = __popcll(mask);
    __syncthreads();
    if (t == 0) {
      int a = 0;
#pragma unroll
      for (int i = 0; i < 4; ++i) { woff[i] = a; a += wtot[i]; }
      sc[b * NCH_ + ch] = a;
    }
    __syncthreads();
    if (pred) {
      const int pos = woff[wv] + __popcll(mask & ((1ULL << lane) - 1ULL));
      ck[(size_t)(b * NCH_ + ch) * 256 + pos] = key;
    }
  } else {
    const int idx = (u - NCH_ * B_) * 256 + t;  // [l][w8][ks][oi2][lane]
    const int lane = idx & 63;
    const int oi = (idx >> 6) & 1;
    const int ks = (idx >> 7) & 7;
    const int w = (idx >> 10) & 7;
    const int l = idx >> 13;
    const int o = w * 32 + oi * 16 + (lane & 15);
    const int k0 = ks * 32 + (lane >> 4) * 8;
    const float* src = W + ((size_t)(l * C_ + o)) * C_ + k0;
    float4 w0 = *(const float4*)&src[0];
    float4 w1 = *(const float4*)&src[4];
    const float wv4[8] = {w0.x, w0.y, w0.z, w0.w, w1.x, w1.y, w1.z, w1.w};
    unsigned short hs[8];
#pragma unroll
    for (int q = 0; q < 8; ++q) hs[q] = f2bf(wv4[q]);
    *(uint4*)&Whi[(size_t)idx * 8] = *(const uint4*)&hs[0];
  }
}

// ---------------------------------------------------------------------------
// K2: exact rank among survivors (block = (j-chunk, b), full i-scan with
// counts in registers) + FUSED scatter keep/out_keep/rnk/boxK/maxiou.
// Ranks of kept survivors cover [0, K) exactly once -> maxiou fully init'd.
__global__ __launch_bounds__(256) void k_rankscat(
    const unsigned long long* __restrict__ ck, const int* __restrict__ sc,
    const float* __restrict__ box, int* __restrict__ keep_i,
    float* __restrict__ out_keep, int* __restrict__ rnk,
    float* __restrict__ boxK, unsigned* __restrict__ maxiou) {
  const int b = blockIdx.y;
  const int jch = blockIdx.x;
  const int t = threadIdx.x;
  __shared__ unsigned long long sk[256];
  __shared__ int scl[NCH_];
  for (int i = t; i < NCH_; i += 256) scl[i] = sc[b * NCH_ + i];
  __syncthreads();
  const bool valid = t < scl[jch];
  const unsigned long long myk =
      valid ? ck[(size_t)(b * NCH_ + jch) * 256 + t] : 0ULL;
  int c = 0;
  for (int ic = 0; ic < NCH_; ++ic) {
    const int sci = scl[ic];
    __syncthreads();
    sk[t] = ck[(size_t)(b * NCH_ + ic) * 256 + t];
    __syncthreads();
    int ii = 0;
    for (; ii + 1 < sci; ii += 2) {
      ull2 v = *(const ull2*)&sk[ii];
      c += (int)(v.x > myk) + (int)(v.y > myk);
    }
    if (ii < sci) c += (int)(sk[ii] > myk);
  }
  if (valid && c < K_) {
    const int n = N_ - 1 - (int)(myk & 0xffffffffu);
    keep_i[b * K_ + c] = n;
    out_keep[b * K_ + c] = (float)n;
    rnk[b * N_ + n] = c;
    const float* bb = box + (size_t)b * 4 * N_;
    float4 v;
    v.x = bb[n]; v.y = bb[N_ + n]; v.z = bb[2 * N_ + n]; v.w = bb[3 * N_ + n];
    ((float4*)boxK)[b * K_ + c] = v;
    maxiou[b * K_ + c] = 0u;
  }
}

// ---------------------------------------------------------------------------
// K3: iou (420 triangular units) + gather/transpose/bf16 (2504 units).
__global__ __launch_bounds__(256) void k_ioug(const float* __restrict__ boxK,
                                              unsigned* __restrict__ maxiou,
                                              const int* __restrict__ rnk,
                                              const float* __restrict__ feat,
                                              unsigned short* __restrict__ Xhi) {
  __shared__ __align__(16) char arena[16640];
  const int u = blockIdx.x;
  const int t = threadIdx.x;
  if (u < 420) {
    const int b = u / 210;
    const int p = u % 210;
    int jt = 0;
    while ((jt + 1) * (jt + 2) / 2 <= p) ++jt;
    const int it = p - jt * (jt + 1) / 2;
    float* sx0 = (float*)arena;
    float* sy0 = sx0 + 256; float* sx1 = sy0 + 256;
    float* sy1 = sx1 + 256; float* sa = sy1 + 256;
    const int gi0 = it * 256;
    const int gl = gi0 + t;
    if (gl < K_) {
      float4 v = ((const float4*)boxK)[b * K_ + gl];
      sx0[t] = v.x; sy0[t] = v.y; sx1[t] = v.z; sy1[t] = v.w;
      sa[t] = __fmul_rn(__fsub_rn(v.z, v.x), __fsub_rn(v.w, v.y));
    } else {
      sx0[t] = 1e30f; sy0[t] = 1e30f; sx1[t] = -1e30f; sy1[t] = -1e30f;
      sa[t] = 0.f;
    }
    __syncthreads();
    const int j = jt * 256 + t;
    if (j >= K_) return;
    float4 v = ((const float4*)boxK)[b * K_ + j];
    const float aj = __fmul_rn(__fsub_rn(v.z, v.x), __fsub_rn(v.w, v.y));
    float mx = 0.f;
    int lim = j - gi0;
    if (lim > 256) lim = 256;
    for (int ii = 0; ii < lim; ++ii) {
      float ltx = fmaxf(sx0[ii], v.x);
      float lty = fmaxf(sy0[ii], v.y);
      float rbx = fminf(sx1[ii], v.z);
      float rby = fminf(sy1[ii], v.w);
      float wx = fmaxf(__fsub_rn(rbx, ltx), 0.f);
      float wy = fmaxf(__fsub_rn(rby, lty), 0.f);
      float inter = __fmul_rn(wx, wy);
      if (inter > 0.f) {
        float uni = __fsub_rn(__fadd_rn(sa[ii], aj), inter);
        mx = fmaxf(mx, __fdiv_rn(inter, uni));
      }
    }
    if (mx > 0.f) atomicMax(&maxiou[b * K_ + j], __float_as_uint(mx));
  } else {
    const int v2 = u - 420;
    const int b = v2 / 1252;
    const int rem = v2 % 1252;
    const int c0 = (rem / 313) * 64;
    const int n0 = (rem % 313) * 64;
    float* T = (float*)arena;  // [64][65]
    const int nl = t & 63, wq = t >> 6;
#pragma unroll
    for (int r = 0; r < 16; ++r) {
      const int cl = r * 4 + wq;
      const int n = n0 + nl;
      T[nl * 65 + cl] =
          (n < N_) ? feat[((size_t)(b * C_ + c0 + cl)) * N_ + n] : 0.f;
    }
    __syncthreads();
    const int nn = n0 + (t >> 2);
    if (nn >= N_) return;
    const int r = rnk[b * N_ + nn];
    if (r >= K_) return;
    const int cseg = (t & 3) * 16;
    unsigned short hb[16];
#pragma unroll
    for (int i = 0; i < 16; ++i)
      hb[i] = f2bf(T[(t >> 2) * 65 + cseg + i]);
    const size_t base = (size_t)(b * K_ + r) * C_ + c0 + cseg;
    *(uint4*)&Xhi[base] = *(const uint4*)&hb[0];
    *(uint4*)&Xhi[base + 8] = *(const uint4*)&hb[8];
  }
}

// ---------------------------------------------------------------------------
// K4: all 6 MLP layers, pure-bf16 operands + f32 MFMA accumulate, activations
// resident in LDS (32 rows/block), 512 threads = 8 waves (wave w owns o in
// [w*32, w*32+32)), then fused final 3-row GEMV + softmax + masked sum.
// W loads: packed layout, base + lane*16B (coalesced 1KB txns).
__global__ __launch_bounds__(512, 2) void k_mlp6(
    const unsigned short* __restrict__ Whi,
    const float* __restrict__ bias, const float* __restrict__ Wf,
    const float* __restrict__ bf, const unsigned* __restrict__ maxiou,
    const unsigned short* __restrict__ Xhi,
    float* __restrict__ out_loc) {
  __shared__ unsigned short act_hi[32 * AST_];
  __shared__ float swf[768];
  const int t = threadIdx.x;
  const int m0 = blockIdx.x * 32;

  {
    const int r = t >> 4;
    const int cs = (t & 15) * 16;
    const size_t g = (size_t)(m0 + r) * C_ + cs;
    *(uint4*)&act_hi[r * AST_ + cs] = *(const uint4*)&Xhi[g];
    *(uint4*)&act_hi[r * AST_ + cs + 8] = *(const uint4*)&Xhi[g + 8];
  }
  for (int i = t; i < 768; i += 512) swf[i] = Wf[i];
  __syncthreads();

  const int lane = t & 63;
  const int w = t >> 6;
  const int quad = lane >> 4, l15 = lane & 15;

  for (int l = 0; l < 6; ++l) {
    const size_t wbase = (size_t)(l * 8 + w) * 8192 + (size_t)lane * 8;
    f32x4 acc[2][2];
#pragma unroll
    for (int mi = 0; mi < 2; ++mi)
#pragma unroll
      for (int oi = 0; oi < 2; ++oi) acc[mi][oi] = (f32x4)0.f;
    uint4 nwh[2];
#pragma unroll
    for (int oi = 0; oi < 2; ++oi)
      nwh[oi] = *(const uint4*)&Whi[wbase + oi * 512];
#pragma unroll
    for (int ks = 0; ks < 8; ++ks) {
      bf16x8 wh[2];
#pragma unroll
      for (int oi = 0; oi < 2; ++oi) wh[oi] = as_bf(nwh[oi]);
      if (ks < 7) {
        const size_t nb = wbase + (size_t)(ks + 1) * 1024;
#pragma unroll
        for (int oi = 0; oi < 2; ++oi)
          nwh[oi] = *(const uint4*)&Whi[nb + oi * 512];
      }
      bf16x8 Ah[2];
#pragma unroll
      for (int mi = 0; mi < 2; ++mi)
        Ah[mi] = *(const bf16x8*)&act_hi[(mi * 16 + l15) * AST_ + ks * 32 + quad * 8];
#pragma unroll
      for (int mi = 0; mi < 2; ++mi)
#pragma unroll
        for (int oi = 0; oi < 2; ++oi)
          acc[mi][oi] = __builtin_amdgcn_mfma_f32_16x16x32_bf16(Ah[mi], wh[oi], acc[mi][oi], 0, 0, 0);
    }
    __syncthreads();
#pragma unroll
    for (int oi = 0; oi < 2; ++oi) {
      const int col = w * 32 + oi * 16 + l15;
      const float bb = bias[l * C_ + col];
#pragma unroll
      for (int mi = 0; mi < 2; ++mi)
#pragma unroll
        for (int r = 0; r < 4; ++r) {
          float y = acc[mi][oi][r] + bb;
          y = fmaxf(y, 0.2f * y);
          act_hi[(mi * 16 + quad * 4 + r) * AST_ + col] = f2bf(y);
        }
    }
    __syncthreads();
  }

  const int r = t >> 4;
  const int part = t & 15;
  const int m = m0 + r;
  float a0 = 0.f, a1 = 0.f, a2 = 0.f;
  for (int c = part * 16; c < part * 16 + 16; c += 2) {
    const unsigned hv = *(const unsigned*)&act_hi[r * AST_ + c];
    const float x0 = __uint_as_float((hv & 0xffffu) << 16);
    const float x1 = __uint_as_float(hv & 0xffff0000u);
    a0 += swf[c] * x0 + swf[c + 1] * x1;
    a1 += swf[256 + c] * x0 + swf[256 + c + 1] * x1;
    a2 += swf[512 + c] * x0 + swf[512 + c + 1] * x1;
  }
#pragma unroll
  for (int off = 1; off < 16; off <<= 1) {
    a0 += __shfl_xor(a0, off);
    a1 += __shfl_xor(a1, off);
    a2 += __shfl_xor(a2, off);
  }
  if (part == 0 && m < M_) {
    a0 += bf[0]; a1 += bf[1]; a2 += bf[2];
    const float mxv = fmaxf(a0, fmaxf(a1, a2));
    const float e0 = expf(a0 - mxv);
    const float e1 = expf(a1 - mxv);
    const float e2 = expf(a2 - mxv);
    const float inv = 1.f / (e0 + e1 + e2);
    const float miou = __uint_as_float(maxiou[m]);
    float loc = 0.f;
    if (miou < 0.4f) loc += e0;
    if (miou < 0.6f) loc += e1;
    if (miou < 0.8f) loc += e2;
    out_loc[m] = loc * inv;
  }
}

// ---------------------------------------------------------------------------
extern "C" void kernel_launch(void* const* d_in, const int* in_sizes, int n_in,
                              void* d_out, int out_size, void* d_ws, size_t ws_size,
                              hipStream_t stream) {
  const float* box   = (const float*)d_in[0];
  const float* score = (const float*)d_in[1];
  const float* feat  = (const float*)d_in[2];
  const float* W     = (const float*)d_in[3];
  const float* bias  = (const float*)d_in[4];
  const float* Wf    = (const float*)d_in[5];
  const float* bf    = (const float*)d_in[6];

  float* out = (float*)d_out;
  float* out_loc  = out;
  float* out_keep = out + M_;

  char* ws = (char*)d_ws;
  int*            keep_i = (int*)(ws + 0);
  float*          boxK   = (float*)(ws + 40960);
  unsigned*       maxiou = (unsigned*)(ws + 201216);
  unsigned short* Whi    = (unsigned short*)(ws + 241664);    // 786432 B
  unsigned short* XtA_hi = (unsigned short*)(ws + 1814528);   // 5177344 B
  int*                rnk = (int*)(ws + 12169216);            // 160000 B
  unsigned long long* ck  = (unsigned long long*)(ws + 12330240);  // 323584 B
  int*                sc  = (int*)(ws + 12654080);            // 632 B

  k_selpack<<<NCH_ * B_ + 192, 256, 0, stream>>>(score, W, Whi, ck, sc, rnk);
  k_rankscat<<<dim3(NCH_, B_), 256, 0, stream>>>(ck, sc, box, keep_i, out_keep,
                                                 rnk, boxK, maxiou);
  k_ioug<<<2924, 256, 0, stream>>>(boxK, maxiou, rnk, feat, XtA_hi);
  k_mlp6<<<313, 512, 0, stream>>>(Whi, bias, Wf, bf, maxiou, XtA_hi, out_loc);
}

// Round 14
// 194.784 us; speedup vs baseline: 1.3623x; 1.3623x over previous
//
#include <hip/hip_runtime.h>

// Problem constants
#define B_  2
#define N_  20000
#define C_  256
#define K_  5000
#define M_  (B_ * K_)     // 10000
#define CAP_ 5376         // survivor capacity per batch
#define NBIN_ 2048
#define AST_ 264          // act LDS row stride (shorts): 16B-aligned
#define RT_  21           // CAP_/256 j-tiles
#define RCH_ 7            // rank chunk count
#define RCT_ 3            // tiles per rank chunk

typedef __attribute__((ext_vector_type(8))) short bf16x8;
typedef __attribute__((ext_vector_type(4))) float f32x4;
typedef __attribute__((ext_vector_type(2))) unsigned long long ull2;

__device__ __forceinline__ unsigned short f2bf(float x) {
  unsigned u = __float_as_uint(x);
  return (unsigned short)((u + 0x7fffu + ((u >> 16) & 1u)) >> 16);
}
__device__ __forceinline__ float bf2f(unsigned short h) {
  return __uint_as_float(((unsigned)h) << 16);
}
__device__ __forceinline__ unsigned fkey(float f) {
  unsigned u = __float_as_uint(f);
  return (u & 0x80000000u) ? ~u : (u | 0x80000000u);
}
// monotone linear bin; only hist/compact CONSISTENCY matters (upward-closed set)
__device__ __forceinline__ int binof(float s) {
  int b = (int)(s * 2048.0f);
  return b < 0 ? 0 : (b > 2047 ? 2047 : b);
}
__device__ __forceinline__ bf16x8 as_bf(uint4 v) {
  union { uint4 u; bf16x8 b; } c; c.u = v; return c.b;
}

// ---------------------------------------------------------------------------
// K1: W f32 -> bf16 (RNE), PRE-PACKED into per-wave MFMA fragment order for
// the 8-wave k_mlp6:  Wp[l][w8][ks][oi2][lane][j]  (j=0..7 shorts)
// holding W[o = w*32 + oi*16 + (lane&15)][k = ks*32 + (lane>>4)*8 + j].
// A wave's W load is then base + lane*16B -> one coalesced 1KB txn.
// Also zeros nc and cnt2.  (Pure-bf16 MLP: no lo residual arrays.)
__global__ __launch_bounds__(256) void k_prep(const float* __restrict__ W,
                                              unsigned short* __restrict__ Whi,
                                              int* __restrict__ nc,
                                              int* __restrict__ cnt2) {
  const int u = blockIdx.x;
  const int t = threadIdx.x;
  if (u >= 192) {
    if (u == 234) { if (t < B_) nc[t] = 0; return; }
    const int i = (u - 192) * 256 + t;
    if (i < B_ * CAP_) cnt2[i] = 0;
    return;
  }
  const int idx = u * 256 + t;  // 0..49151 = [l][w][ks][oi][lane]
  const int lane = idx & 63;
  const int oi = (idx >> 6) & 1;
  const int ks = (idx >> 7) & 7;
  const int w = (idx >> 10) & 7;
  const int l = idx >> 13;
  const int o = w * 32 + oi * 16 + (lane & 15);
  const int k0 = ks * 32 + (lane >> 4) * 8;
  const float* src = W + ((size_t)(l * C_ + o)) * C_ + k0;
  float4 w0 = *(const float4*)&src[0];
  float4 w1 = *(const float4*)&src[4];
  const float wv[8] = {w0.x, w0.y, w0.z, w0.w, w1.x, w1.y, w1.z, w1.w};
  unsigned short hs[8];
#pragma unroll
  for (int q = 0; q < 8; ++q) hs[q] = f2bf(wv[q]);
  *(uint4*)&Whi[(size_t)idx * 8] = *(const uint4*)&hs[0];
}

// ---------------------------------------------------------------------------
// K2: per-block LDS histogram + select threshold bin + compact survivors.
__global__ __launch_bounds__(256) void k_selcomp(const float* __restrict__ score,
                                                 int* __restrict__ nc,
                                                 unsigned long long* __restrict__ ck,
                                                 int* __restrict__ rnk) {
  const int b = blockIdx.y;
  const float* s = score + b * N_;
  __shared__ int h[NBIN_];
  __shared__ int chs[256];
  __shared__ int res[1];
  const int t = threadIdx.x;
  for (int i = t; i < NBIN_; i += 256) h[i] = 0;
  __syncthreads();
  for (int i = t; i < N_; i += 256) atomicAdd(&h[binof(s[i])], 1);
  __syncthreads();
  int sum = 0;
#pragma unroll
  for (int j = 0; j < 8; ++j) sum += h[t * 8 + j];
  chs[t] = sum;
  __syncthreads();
  for (int off = 1; off < 256; off <<= 1) {
    int v = chs[t] + ((t + off < 256) ? chs[t + off] : 0);
    __syncthreads();
    chs[t] = v;
    __syncthreads();
  }
  const int above = (t + 1 < 256) ? chs[t + 1] : 0;
  if (above < K_ && K_ <= chs[t]) {
    int acc = above;
    for (int i = 7; i >= 0; --i) {
      const int bin = t * 8 + i;
      if (acc + h[bin] >= K_) { res[0] = bin; break; }
      acc += h[bin];
    }
  }
  __syncthreads();
  const int selB = res[0];
  const int n = blockIdx.x * 256 + t;
  if (n < N_) {
    rnk[b * N_ + n] = K_;
    const float sv = s[n];
    if (binof(sv) >= selB) {
      const int pos = atomicAdd(&nc[b], 1);
      if (pos < CAP_)
        ck[b * CAP_ + pos] =
            ((unsigned long long)fkey(sv) << 32) | (unsigned)(N_ - 1 - n);
    }
  }
}

// ---------------------------------------------------------------------------
// K3: partial exact rank among survivors (chunked for occupancy: 294 blocks).
__global__ __launch_bounds__(256) void k_rank2(const int* __restrict__ nc,
                                               const unsigned long long* __restrict__ ck,
                                               int* __restrict__ cnt2) {
  const int b = blockIdx.z;
  int S = nc[b]; if (S > CAP_) S = CAP_;
  __shared__ unsigned long long sk[256];
  const int t = threadIdx.x;
  const int j = blockIdx.x * 256 + t;
  const unsigned long long* kb = ck + b * CAP_;
  const unsigned long long myk = (j < S) ? kb[j] : 0ULL;
  int c = 0;
  const int nt = (S + 255) >> 8;
  int t0 = blockIdx.y * RCT_, t1 = t0 + RCT_;
  if (t1 > nt) t1 = nt;
  for (int tt = t0; tt < t1; ++tt) {
    const int gi = tt * 256 + t;
    unsigned long long kk = (gi < S) ? kb[gi] : 0ULL;
    __syncthreads();
    sk[t] = kk;
    __syncthreads();
#pragma unroll 8
    for (int ii = 0; ii < 256; ii += 2) {
      ull2 v = *(const ull2*)&sk[ii];
      c += (int)(v.x > myk) + (int)(v.y > myk);
    }
  }
  if (j < S && c > 0) atomicAdd(&cnt2[b * CAP_ + j], c);
}

// ---------------------------------------------------------------------------
// K4: scatter keep/out_keep/rnk/boxK/maxiou from final ranks.
__global__ __launch_bounds__(256) void k_scatter2(const int* __restrict__ nc,
                                                  const unsigned long long* __restrict__ ck,
                                                  const int* __restrict__ cnt2,
                                                  const float* __restrict__ box,
                                                  int* __restrict__ keep_i,
                                                  float* __restrict__ out_keep,
                                                  int* __restrict__ rnk,
                                                  float* __restrict__ boxK,
                                                  unsigned* __restrict__ maxiou) {
  const int b = blockIdx.y;
  int S = nc[b]; if (S > CAP_) S = CAP_;
  const int j = blockIdx.x * 256 + threadIdx.x;
  if (j >= S) return;
  const int c = cnt2[b * CAP_ + j];
  if (c >= K_) return;
  const int n = N_ - 1 - (int)(ck[b * CAP_ + j] & 0xffffffffu);
  keep_i[b * K_ + c] = n;
  out_keep[b * K_ + c] = (float)n;
  rnk[b * N_ + n] = c;
  const float* bb = box + (size_t)b * 4 * N_;
  float4 v;
  v.x = bb[n]; v.y = bb[N_ + n]; v.z = bb[2 * N_ + n]; v.w = bb[3 * N_ + n];
  ((float4*)boxK)[b * K_ + c] = v;
  maxiou[b * K_ + c] = 0u;
}

// ---------------------------------------------------------------------------
// K5: iou (420 triangular units) + gather/transpose/bf16 (2504 units).
__global__ __launch_bounds__(256) void k_ioug(const float* __restrict__ boxK,
                                              unsigned* __restrict__ maxiou,
                                              const int* __restrict__ rnk,
                                              const float* __restrict__ feat,
                                              unsigned short* __restrict__ Xhi) {
  __shared__ __align__(16) char arena[16640];
  const int u = blockIdx.x;
  const int t = threadIdx.x;
  if (u < 420) {
    const int b = u / 210;
    const int p = u % 210;
    int jt = 0;
    while ((jt + 1) * (jt + 2) / 2 <= p) ++jt;
    const int it = p - jt * (jt + 1) / 2;
    float* sx0 = (float*)arena;
    float* sy0 = sx0 + 256; float* sx1 = sy0 + 256;
    float* sy1 = sx1 + 256; float* sa = sy1 + 256;
    const int gi0 = it * 256;
    const int gl = gi0 + t;
    if (gl < K_) {
      float4 v = ((const float4*)boxK)[b * K_ + gl];
      sx0[t] = v.x; sy0[t] = v.y; sx1[t] = v.z; sy1[t] = v.w;
      sa[t] = __fmul_rn(__fsub_rn(v.z, v.x), __fsub_rn(v.w, v.y));
    } else {
      sx0[t] = 1e30f; sy0[t] = 1e30f; sx1[t] = -1e30f; sy1[t] = -1e30f;
      sa[t] = 0.f;
    }
    __syncthreads();
    const int j = jt * 256 + t;
    if (j >= K_) return;
    float4 v = ((const float4*)boxK)[b * K_ + j];
    const float aj = __fmul_rn(__fsub_rn(v.z, v.x), __fsub_rn(v.w, v.y));
    float mx = 0.f;
    int lim = j - gi0;
    if (lim > 256) lim = 256;
    for (int ii = 0; ii < lim; ++ii) {
      float ltx = fmaxf(sx0[ii], v.x);
      float lty = fmaxf(sy0[ii], v.y);
      float rbx = fminf(sx1[ii], v.z);
      float rby = fminf(sy1[ii], v.w);
      float wx = fmaxf(__fsub_rn(rbx, ltx), 0.f);
      float wy = fmaxf(__fsub_rn(rby, lty), 0.f);
      float inter = __fmul_rn(wx, wy);
      if (inter > 0.f) {
        float uni = __fsub_rn(__fadd_rn(sa[ii], aj), inter);
        mx = fmaxf(mx, __fdiv_rn(inter, uni));
      }
    }
    if (mx > 0.f) atomicMax(&maxiou[b * K_ + j], __float_as_uint(mx));
  } else {
    const int v2 = u - 420;
    const int b = v2 / 1252;
    const int rem = v2 % 1252;
    const int c0 = (rem / 313) * 64;
    const int n0 = (rem % 313) * 64;
    float* T = (float*)arena;  // [64][65]
    const int nl = t & 63, wq = t >> 6;
#pragma unroll
    for (int r = 0; r < 16; ++r) {
      const int cl = r * 4 + wq;
      const int n = n0 + nl;
      T[nl * 65 + cl] =
          (n < N_) ? feat[((size_t)(b * C_ + c0 + cl)) * N_ + n] : 0.f;
    }
    __syncthreads();
    const int nn = n0 + (t >> 2);
    if (nn >= N_) return;
    const int r = rnk[b * N_ + nn];
    if (r >= K_) return;
    const int cseg = (t & 3) * 16;
    unsigned short hb[16];
#pragma unroll
    for (int i = 0; i < 16; ++i)
      hb[i] = f2bf(T[(t >> 2) * 65 + cseg + i]);
    const size_t base = (size_t)(b * K_ + r) * C_ + c0 + cseg;
    *(uint4*)&Xhi[base] = *(const uint4*)&hb[0];
    *(uint4*)&Xhi[base + 8] = *(const uint4*)&hb[8];
  }
}

// ---------------------------------------------------------------------------
// K6: all 6 MLP layers, pure-bf16 operands + f32 MFMA accumulate, activations
// resident in LDS (32 rows/block), 512 threads = 8 waves (wave w owns o in
// [w*32, w*32+32)), then fused final 3-row GEMV + softmax + masked sum.
// W loads: packed layout, base + lane*16B (coalesced 1KB txns).
__global__ __launch_bounds__(512, 2) void k_mlp6(
    const unsigned short* __restrict__ Whi,
    const float* __restrict__ bias, const float* __restrict__ Wf,
    const float* __restrict__ bf, const unsigned* __restrict__ maxiou,
    const unsigned short* __restrict__ Xhi,
    float* __restrict__ out_loc) {
  __shared__ unsigned short act_hi[32 * AST_];
  __shared__ float swf[768];
  const int t = threadIdx.x;
  const int m0 = blockIdx.x * 32;

  // stage initial activations (coalesced): thread = (row t>>4, 16-col seg)
  {
    const int r = t >> 4;
    const int cs = (t & 15) * 16;
    const size_t g = (size_t)(m0 + r) * C_ + cs;
    *(uint4*)&act_hi[r * AST_ + cs] = *(const uint4*)&Xhi[g];
    *(uint4*)&act_hi[r * AST_ + cs + 8] = *(const uint4*)&Xhi[g + 8];
  }
  for (int i = t; i < 768; i += 512) swf[i] = Wf[i];
  __syncthreads();

  const int lane = t & 63;
  const int w = t >> 6;            // wave id -> o base w*32
  const int quad = lane >> 4, l15 = lane & 15;

  for (int l = 0; l < 6; ++l) {
    // packed W (shorts): (l*8+w)*8192 + ks*1024 + oi*512 + lane*8
    const size_t wbase = (size_t)(l * 8 + w) * 8192 + (size_t)lane * 8;
    f32x4 acc[2][2];
#pragma unroll
    for (int mi = 0; mi < 2; ++mi)
#pragma unroll
      for (int oi = 0; oi < 2; ++oi) acc[mi][oi] = (f32x4)0.f;
    uint4 nwh[2];
#pragma unroll
    for (int oi = 0; oi < 2; ++oi)
      nwh[oi] = *(const uint4*)&Whi[wbase + oi * 512];
#pragma unroll
    for (int ks = 0; ks < 8; ++ks) {
      bf16x8 wh[2];
#pragma unroll
      for (int oi = 0; oi < 2; ++oi) wh[oi] = as_bf(nwh[oi]);
      if (ks < 7) {
        const size_t nb = wbase + (size_t)(ks + 1) * 1024;
#pragma unroll
        for (int oi = 0; oi < 2; ++oi)
          nwh[oi] = *(const uint4*)&Whi[nb + oi * 512];
      }
      bf16x8 Ah[2];
#pragma unroll
      for (int mi = 0; mi < 2; ++mi)
        Ah[mi] = *(const bf16x8*)&act_hi[(mi * 16 + l15) * AST_ + ks * 32 + quad * 8];
#pragma unroll
      for (int mi = 0; mi < 2; ++mi)
#pragma unroll
        for (int oi = 0; oi < 2; ++oi)
          acc[mi][oi] = __builtin_amdgcn_mfma_f32_16x16x32_bf16(Ah[mi], wh[oi], acc[mi][oi], 0, 0, 0);
    }
    __syncthreads();  // all A reads done before overwrite
#pragma unroll
    for (int oi = 0; oi < 2; ++oi) {
      const int col = w * 32 + oi * 16 + l15;
      const float bb = bias[l * C_ + col];
#pragma unroll
      for (int mi = 0; mi < 2; ++mi)
#pragma unroll
        for (int r = 0; r < 4; ++r) {
          float y = acc[mi][oi][r] + bb;
          y = fmaxf(y, 0.2f * y);
          act_hi[(mi * 16 + quad * 4 + r) * AST_ + col] = f2bf(y);
        }
    }
    __syncthreads();
  }

  // fused final: 16 threads per row, partial GEMV + shuffle reduce
  const int r = t >> 4;
  const int part = t & 15;
  const int m = m0 + r;
  float a0 = 0.f, a1 = 0.f, a2 = 0.f;
  for (int c = part * 16; c < part * 16 + 16; c += 2) {
    const unsigned hv = *(const unsigned*)&act_hi[r * AST_ + c];
    const float x0 = __uint_as_float((hv & 0xffffu) << 16);
    const float x1 = __uint_as_float(hv & 0xffff0000u);
    a0 += swf[c] * x0 + swf[c + 1] * x1;
    a1 += swf[256 + c] * x0 + swf[256 + c + 1] * x1;
    a2 += swf[512 + c] * x0 + swf[512 + c + 1] * x1;
  }
#pragma unroll
  for (int off = 1; off < 16; off <<= 1) {
    a0 += __shfl_xor(a0, off);
    a1 += __shfl_xor(a1, off);
    a2 += __shfl_xor(a2, off);
  }
  if (part == 0 && m < M_) {
    a0 += bf[0]; a1 += bf[1]; a2 += bf[2];
    const float mxv = fmaxf(a0, fmaxf(a1, a2));
    const float e0 = expf(a0 - mxv);
    const float e1 = expf(a1 - mxv);
    const float e2 = expf(a2 - mxv);
    const float inv = 1.f / (e0 + e1 + e2);
    const float miou = __uint_as_float(maxiou[m]);
    float loc = 0.f;
    if (miou < 0.4f) loc += e0;
    if (miou < 0.6f) loc += e1;
    if (miou < 0.8f) loc += e2;
    out_loc[m] = loc * inv;
  }
}

// ---------------------------------------------------------------------------
extern "C" void kernel_launch(void* const* d_in, const int* in_sizes, int n_in,
                              void* d_out, int out_size, void* d_ws, size_t ws_size,
                              hipStream_t stream) {
  const float* box   = (const float*)d_in[0];
  const float* score = (const float*)d_in[1];
  const float* feat  = (const float*)d_in[2];
  const float* W     = (const float*)d_in[3];
  const float* bias  = (const float*)d_in[4];
  const float* Wf    = (const float*)d_in[5];
  const float* bf    = (const float*)d_in[6];

  float* out = (float*)d_out;
  float* out_loc  = out;
  float* out_keep = out + M_;

  char* ws = (char*)d_ws;
  int*            keep_i = (int*)(ws + 0);
  float*          boxK   = (float*)(ws + 40960);
  unsigned*       maxiou = (unsigned*)(ws + 201216);
  unsigned short* Whi    = (unsigned short*)(ws + 241664);
  unsigned short* XtA_hi = (unsigned short*)(ws + 1814528);
  int*                rnk    = (int*)(ws + 12169216);
  unsigned long long* ck     = (unsigned long long*)(ws + 12329216);
  int*                cnt2   = (int*)(ws + 12415232);
  int*                nc     = (int*)(ws + 12458240);

  k_prep<<<235, 256, 0, stream>>>(W, Whi, nc, cnt2);
  k_selcomp<<<dim3(79, B_), 256, 0, stream>>>(score, nc, ck, rnk);
  k_rank2<<<dim3(RT_, RCH_, B_), 256, 0, stream>>>(nc, ck, cnt2);
  k_scatter2<<<dim3(RT_, B_), 256, 0, stream>>>(nc, ck, cnt2, box, keep_i,
                                                out_keep, rnk, boxK, maxiou);
  k_ioug<<<2924, 256, 0, stream>>>(boxK, maxiou, rnk, feat, XtA_hi);
  k_mlp6<<<313, 512, 0, stream>>>(Whi, bias, Wf, bf, maxiou, XtA_hi, out_loc);
}